// Round 10
// baseline (545.803 us; speedup 1.0000x reference)
//
#include <hip/hip_runtime.h>

typedef __attribute__((ext_vector_type(8))) short short8;
typedef __attribute__((ext_vector_type(4))) float f32x4;

__device__ __forceinline__ float bf2f(unsigned short u){
  return __uint_as_float(((unsigned int)u) << 16);
}
__device__ __forceinline__ unsigned short f2bf(float f){
  unsigned int u = __float_as_uint(f);
  u += 0x7fffu + ((u >> 16) & 1u);   // RNE
  return (unsigned short)(u >> 16);
}
// dtype-dispatching scalar load: isF32 ? f32[i] : bf16[i]
__device__ __forceinline__ float ldf(const void* p, long i, int isF32){
  return isF32 ? ((const float*)p)[i] : bf2f(((const unsigned short*)p)[i]);
}

// ---- prep: dtype detect (block 0) + row_ptr from sorted rows ----
__global__ void prep_k(const int* __restrict__ rows, int* __restrict__ rs,
                       int E, int N, const unsigned short* __restrict__ x,
                       int* __restrict__ flag){
  if (blockIdx.x == 0){
    __shared__ int s;
    if (threadIdx.x == 0) s = 0;
    __syncthreads();
    int bad = 0;
    for (int i = threadIdx.x; i < 2048; i += 256){
      unsigned int e = ((unsigned int)x[2 * i] >> 7) & 0xffu;
      if (e >= 0xF0u) bad = 1;
    }
    if (bad) atomicOr(&s, 1);
    __syncthreads();
    if (threadIdx.x == 0) *flag = s;
  }
  int e = blockIdx.x * 256 + threadIdx.x;
  if (e >= E) return;
  if (e == 0){
    for (int r = 0; r <= rows[0]; ++r) rs[r] = 0;
  } else {
    int a = rows[e - 1], b = rows[e];
    for (int r = a + 1; r <= b; ++r) rs[r] = e;
  }
  if (e == E - 1){
    for (int r = rows[E - 1] + 1; r <= N; ++r) rs[r] = E;
  }
}

// ---- fused transpose of all three W matrices -> canonical bf16 WT ----
__global__ void wtrans_all(const void* __restrict__ Wres,
                           const void* __restrict__ W1,
                           const void* __restrict__ W2,
                           unsigned short* __restrict__ WresT,
                           unsigned short* __restrict__ W1T,
                           unsigned short* __restrict__ W2T,
                           const int* __restrict__ flag){
  int isF32 = *flag;
  int b = blockIdx.x;
  const void* W; unsigned short* WT; int K; int idx;
  if (b < 128)      { W = Wres; WT = WresT; K = 256; idx = b * 256 + threadIdx.x; }
  else if (b < 256) { W = W1;   WT = W1T;   K = 256; idx = (b - 128) * 256 + threadIdx.x; }
  else              { W = W2;   WT = W2T;   K = 128; idx = (b - 256) * 256 + threadIdx.x; }
  if (idx >= K * 128) return;
  int n = idx / K, k = idx - n * K;
  WT[idx] = f2bf(ldf(W, (long)k * 128 + n, isF32));
}

// ============================================================
// Persistent dual-plane GEMM: blockIdx.y=0 -> z = x@Wres + bres,
// blockIdx.y=1 -> y1 = x@W1.  Whole W [128][256] staged ONCE in
// 64 KB LDS (XOR-chunk swizzle); then a BARRIER-FREE grid-stride
// loop over 128-row tiles: batched A loads (MLP 16) -> 128 MFMA
// vs resident LDS -> store.  Waves drift freely; A latency hides
// under other waves' MFMA.  2 blocks/CU (LDS-capped).
// ============================================================
__global__ __launch_bounds__(256, 2) void gemm_zy1_p(
    const void* __restrict__ A,
    const unsigned short* __restrict__ WT0,  // WresT [128][256]
    const unsigned short* __restrict__ WT1,  // W1T   [128][256]
    const void* __restrict__ bias0,
    unsigned short* __restrict__ out0,       // z  [M][128] bf16
    unsigned short* __restrict__ out1,       // y1 [M][128] bf16
    int M, const int* __restrict__ flagp)
{
  constexpr int K = 256;
  __shared__ __align__(16) unsigned short lW[128 * 256];   // 64 KB

  const int fl    = *flagp;
  const int tid   = threadIdx.x;
  const int lane  = tid & 63;
  const int wav   = tid >> 6;
  const int l16   = lane & 15;
  const int quad  = lane >> 4;
  const int plane = blockIdx.y;
  const unsigned short* WT = plane ? WT1 : WT0;
  unsigned short* out      = plane ? out1 : out0;

  // ---- stage whole W once: 4096 16B-chunks / 256 threads ----
#pragma unroll
  for (int j = 0; j < 16; ++j){
    int i = tid + j * 256;
    int n = i >> 5, c = i & 31;                       // n: out-col, c: K-chunk
    *(short8*)&lW[n * 256 + ((c ^ (n & 7)) * 8)] =
        *(const short8*)&WT[n * 256 + c * 8];
  }
  __syncthreads();   // the ONLY barrier

  const int nTiles = (M + 127) >> 7;
  for (int tile = blockIdx.x; tile < nTiles; tile += gridDim.x){
    const int rowBase = tile * 128 + wav * 32;

    // ---- batched A fragment loads for the FULL K=256 ----
    short8 af[2][8];
    if (fl){
#pragma unroll
      for (int s = 0; s < 2; ++s){
        int r = rowBase + s * 16 + l16;
        const float* Af = (const float*)A + (long)r * K + quad * 8;
        f32x4 t0[8], t1[8];
#pragma unroll
        for (int q = 0; q < 8; ++q){
          if (r < M){
            t0[q] = *(const f32x4*)(Af + q * 32);
            t1[q] = *(const f32x4*)(Af + q * 32 + 4);
          } else {
            t0[q] = (f32x4){0.f, 0.f, 0.f, 0.f};
            t1[q] = (f32x4){0.f, 0.f, 0.f, 0.f};
          }
        }
#pragma unroll
        for (int q = 0; q < 8; ++q){
          short8 v;
          v[0] = (short)f2bf(t0[q][0]); v[1] = (short)f2bf(t0[q][1]);
          v[2] = (short)f2bf(t0[q][2]); v[3] = (short)f2bf(t0[q][3]);
          v[4] = (short)f2bf(t1[q][0]); v[5] = (short)f2bf(t1[q][1]);
          v[6] = (short)f2bf(t1[q][2]); v[7] = (short)f2bf(t1[q][3]);
          af[s][q] = v;
        }
      }
    } else {
#pragma unroll
      for (int s = 0; s < 2; ++s){
        int r = rowBase + s * 16 + l16;
        const unsigned short* Ab = (const unsigned short*)A + (long)r * K + quad * 8;
#pragma unroll
        for (int q = 0; q < 8; ++q){
          short8 v = {};
          if (r < M) v = *(const short8*)(Ab + q * 32);
          af[s][q] = v;
        }
      }
    }

    f32x4 acc[2][8];
#pragma unroll
    for (int s = 0; s < 2; ++s)
#pragma unroll
      for (int nt = 0; nt < 8; ++nt) acc[s][nt] = (f32x4){0.f, 0.f, 0.f, 0.f};

    // ---- 128 MFMA vs LDS-resident W, no barriers ----
#pragma unroll
    for (int q = 0; q < 8; ++q){
#pragma unroll
      for (int nt = 0; nt < 8; ++nt){
        int row = nt * 16 + l16;
        int ch  = (q * 4 + quad) ^ (row & 7);
        short8 b = *(const short8*)&lW[row * 256 + ch * 8];
        acc[0][nt] = __builtin_amdgcn_mfma_f32_16x16x32_bf16(af[0][q], b, acc[0][nt], 0, 0, 0);
        acc[1][nt] = __builtin_amdgcn_mfma_f32_16x16x32_bf16(af[1][q], b, acc[1][nt], 0, 0, 0);
      }
    }

    // ---- epilogue ----
#pragma unroll
    for (int s = 0; s < 2; ++s){
      int r0 = rowBase + s * 16 + quad * 4;
#pragma unroll
      for (int nt = 0; nt < 8; ++nt){
        int col = nt * 16 + l16;
        float bv = plane ? 0.0f : ldf(bias0, col, fl);
#pragma unroll
        for (int rg = 0; rg < 4; ++rg){
          int r = r0 + rg;
          if (r < M) out[(long)r * 128 + col] = f2bf(acc[s][nt][rg] + bv);
        }
      }
    }
  }
}

// ============================================================
// Persistent y2 GEMM: y2 = x1(bf16)@W2.  Whole W2 [128][128]
// staged once in 32 KB LDS; barrier-free tile loop; 3 blocks/CU.
// ============================================================
__global__ __launch_bounds__(256, 3) void gemm_y2_p(
    const unsigned short* __restrict__ A,    // x1 bf16 [M][128]
    const unsigned short* __restrict__ WT,   // W2T [128][128]
    unsigned short* __restrict__ out,        // y2 bf16 [M][128]
    int M)
{
  constexpr int K = 128;
  __shared__ __align__(16) unsigned short lW[128 * 128];   // 32 KB

  const int tid  = threadIdx.x;
  const int lane = tid & 63;
  const int wav  = tid >> 6;
  const int l16  = lane & 15;
  const int quad = lane >> 4;

#pragma unroll
  for (int j = 0; j < 8; ++j){
    int i = tid + j * 256;
    int n = i >> 4, c = i & 15;
    *(short8*)&lW[n * 128 + ((c ^ (n & 7)) * 8)] =
        *(const short8*)&WT[n * 128 + c * 8];
  }
  __syncthreads();   // the ONLY barrier

  const int nTiles = (M + 127) >> 7;
  for (int tile = blockIdx.x; tile < nTiles; tile += gridDim.x){
    const int rowBase = tile * 128 + wav * 32;
    short8 af[2][4];
#pragma unroll
    for (int s = 0; s < 2; ++s){
      int r = rowBase + s * 16 + l16;
      const unsigned short* Ab = A + (long)r * K + quad * 8;
#pragma unroll
      for (int q = 0; q < 4; ++q){
        short8 v = {};
        if (r < M) v = *(const short8*)(Ab + q * 32);
        af[s][q] = v;
      }
    }
    f32x4 acc[2][8];
#pragma unroll
    for (int s = 0; s < 2; ++s)
#pragma unroll
      for (int nt = 0; nt < 8; ++nt) acc[s][nt] = (f32x4){0.f, 0.f, 0.f, 0.f};
#pragma unroll
    for (int q = 0; q < 4; ++q){
#pragma unroll
      for (int nt = 0; nt < 8; ++nt){
        int row = nt * 16 + l16;
        int ch  = (q * 4 + quad) ^ (row & 7);
        short8 b = *(const short8*)&lW[row * 128 + ch * 8];
        acc[0][nt] = __builtin_amdgcn_mfma_f32_16x16x32_bf16(af[0][q], b, acc[0][nt], 0, 0, 0);
        acc[1][nt] = __builtin_amdgcn_mfma_f32_16x16x32_bf16(af[1][q], b, acc[1][nt], 0, 0, 0);
      }
    }
#pragma unroll
    for (int s = 0; s < 2; ++s){
      int r0 = rowBase + s * 16 + quad * 4;
#pragma unroll
      for (int nt = 0; nt < 8; ++nt){
        int col = nt * 16 + l16;
#pragma unroll
        for (int rg = 0; rg < 4; ++rg){
          int r = r0 + rg;
          if (r < M) out[(long)r * 128 + col] = f2bf(acc[s][nt][rg]);
        }
      }
    }
  }
}

// ---- R0-measured row-parallel gather: 2 feats/lane, MLP-4, scalar tail ----
__device__ __forceinline__ void row_gather(
    int e0, int e1, const int* __restrict__ cols, const void* __restrict__ vals,
    const unsigned short* __restrict__ Y, int lane, int fl,
    float& outx, float& outy)
{
  float ax0 = 0.f, ay0 = 0.f, ax1 = 0.f, ay1 = 0.f;
  int e = e0;
  for (; e + 4 <= e1; e += 4){
    int c0 = cols[e], c1 = cols[e + 1], c2 = cols[e + 2], c3 = cols[e + 3];
    float v0 = ldf(vals, e, fl),     v1 = ldf(vals, e + 1, fl);
    float v2 = ldf(vals, e + 2, fl), v3 = ldf(vals, e + 3, fl);
    unsigned int q0 = *(const unsigned int*)&Y[(long)c0 * 128 + 2 * lane];
    unsigned int q1 = *(const unsigned int*)&Y[(long)c1 * 128 + 2 * lane];
    unsigned int q2 = *(const unsigned int*)&Y[(long)c2 * 128 + 2 * lane];
    unsigned int q3 = *(const unsigned int*)&Y[(long)c3 * 128 + 2 * lane];
    ax0 = fmaf(v0, bf2f((unsigned short)(q0 & 0xffffu)), ax0);
    ay0 = fmaf(v0, bf2f((unsigned short)(q0 >> 16)),     ay0);
    ax1 = fmaf(v1, bf2f((unsigned short)(q1 & 0xffffu)), ax1);
    ay1 = fmaf(v1, bf2f((unsigned short)(q1 >> 16)),     ay1);
    ax0 = fmaf(v2, bf2f((unsigned short)(q2 & 0xffffu)), ax0);
    ay0 = fmaf(v2, bf2f((unsigned short)(q2 >> 16)),     ay0);
    ax1 = fmaf(v3, bf2f((unsigned short)(q3 & 0xffffu)), ax1);
    ay1 = fmaf(v3, bf2f((unsigned short)(q3 >> 16)),     ay1);
  }
  for (; e < e1; ++e){
    int c = cols[e];
    float v = ldf(vals, e, fl);
    unsigned int q = *(const unsigned int*)&Y[(long)c * 128 + 2 * lane];
    ax0 = fmaf(v, bf2f((unsigned short)(q & 0xffffu)), ax0);
    ay0 = fmaf(v, bf2f((unsigned short)(q >> 16)),     ay0);
  }
  outx = ax0 + ax1;
  outy = ay0 + ay1;
}

// ---- spmm1 fused: x1[r] = relu(spmm(y1)[r] + b1) + z[r], bf16 out ----
__global__ __launch_bounds__(256) void spmm1_f(
    const int* __restrict__ rs, const int* __restrict__ cols,
    const void* __restrict__ vals, const unsigned short* __restrict__ Y,
    const unsigned short* __restrict__ z, const void* __restrict__ b1,
    unsigned short* __restrict__ x1, int N, const int* __restrict__ flagp)
{
  const int fl   = *flagp;
  const int lane = threadIdx.x & 63;
  const int wav  = threadIdx.x >> 6;
  int r = blockIdx.x * 4 + wav;
  if (r >= N) return;
  int e0 = __builtin_amdgcn_readfirstlane(rs[r]);
  int e1 = __builtin_amdgcn_readfirstlane(rs[r + 1]);
  float ax, ay;
  row_gather(e0, e1, cols, vals, Y, lane, fl, ax, ay);
  long o = (long)r * 128 + 2 * lane;
  float b0 = ldf(b1, 2 * lane, fl), b1v = ldf(b1, 2 * lane + 1, fl);
  unsigned int zz = *(const unsigned int*)&z[o];
  float r0 = fmaxf(ax + b0,  0.f) + bf2f((unsigned short)(zz & 0xffffu));
  float r1 = fmaxf(ay + b1v, 0.f) + bf2f((unsigned short)(zz >> 16));
  *(unsigned int*)&x1[o] = (unsigned int)f2bf(r0) | ((unsigned int)f2bf(r1) << 16);
}

// ---- spmm2 fused: out[r] = log_softmax(spmm(y2)[r] + b2), dtype per flag ----
__global__ __launch_bounds__(256) void spmm2_f(
    const int* __restrict__ rs, const int* __restrict__ cols,
    const void* __restrict__ vals, const unsigned short* __restrict__ Y,
    const void* __restrict__ b2, void* __restrict__ out, int N,
    const int* __restrict__ flagp)
{
  const int fl   = *flagp;
  const int lane = threadIdx.x & 63;
  const int wav  = threadIdx.x >> 6;
  int r = blockIdx.x * 4 + wav;
  if (r >= N) return;
  int e0 = __builtin_amdgcn_readfirstlane(rs[r]);
  int e1 = __builtin_amdgcn_readfirstlane(rs[r + 1]);
  float ax, ay;
  row_gather(e0, e1, cols, vals, Y, lane, fl, ax, ay);
  float v0 = ax + ldf(b2, 2 * lane, fl);
  float v1 = ay + ldf(b2, 2 * lane + 1, fl);
  float m = fmaxf(v0, v1);
#pragma unroll
  for (int off = 32; off; off >>= 1) m = fmaxf(m, __shfl_xor(m, off));
  float s = expf(v0 - m) + expf(v1 - m);
#pragma unroll
  for (int off = 32; off; off >>= 1) s += __shfl_xor(s, off);
  float lse = m + logf(s);
  long o = (long)r * 128 + 2 * lane;
  if (fl){
    float2 w; w.x = v0 - lse; w.y = v1 - lse;
    *(float2*)&((float*)out)[o] = w;
  } else {
    *(unsigned int*)&((unsigned short*)out)[o] =
        (unsigned int)f2bf(v0 - lse) | ((unsigned int)f2bf(v1 - lse) << 16);
  }
}

extern "C" void kernel_launch(void* const* d_in, const int* in_sizes, int n_in,
                              void* d_out, int out_size, void* d_ws, size_t ws_size,
                              hipStream_t stream)
{
  const void* x    = d_in[0];
  const int*  erow = (const int*)d_in[1];
  const int*  ecol = (const int*)d_in[2];
  const void* eval = d_in[3];
  const void* Wres = d_in[4];
  const void* bres = d_in[5];
  const void* W1   = d_in[6];
  const void* b1   = d_in[7];
  const void* W2   = d_in[8];
  const void* b2   = d_in[9];
  const int N = in_sizes[0] / 256;   // 100000
  const int E = in_sizes[1];         // 1600000

  char* ws = (char*)d_ws;
  size_t szB = (size_t)N * 128 * 2;  // one bf16 [N,128] plane (25.6 MB)
  unsigned short* bufA  = (unsigned short*)ws;            // y1, then y2
  unsigned short* bufC  = (unsigned short*)(ws + szB);    // x1
  unsigned short* WresT = (unsigned short*)(ws + 2 * szB);
  unsigned short* W1T   = WresT + 256 * 128;
  unsigned short* W2T   = W1T   + 256 * 128;
  int*            flag  = (int*)(W2T + 256 * 128);
  int*            rs    = flag + 4;                        // [N+1] row_ptr
  unsigned short* zbuf  = (unsigned short*)d_out;          // z (bf16) in d_out

  prep_k<<<(E + 255) / 256, 256, 0, stream>>>(erow, rs, E, N,
                                              (const unsigned short*)x, flag);
  wtrans_all<<<320, 256, 0, stream>>>(Wres, W1, W2, WresT, W1T, W2T, flag);

  const int rBlocks = (N + 3) / 4;

  dim3 gDual(256, 2);   // 2 blocks/CU, one per plane
  gemm_zy1_p<<<gDual, 256, 0, stream>>>(x, WresT, W1T, bres, zbuf, bufA, N, flag); // z + y1

  spmm1_f<<<rBlocks, 256, 0, stream>>>(rs, ecol, eval, bufA, zbuf, b1, bufC, N, flag); // x1

  gemm_y2_p<<<768, 256, 0, stream>>>(bufC, W2T, bufA, N);                              // y2

  spmm2_f<<<rBlocks, 256, 0, stream>>>(rs, ecol, eval, bufA, b2, d_out, N, flag);      // out
}